// Round 1
// 866.078 us; speedup vs baseline: 1.0033x; 1.0033x over previous
//
#include <hip/hip_runtime.h>
#include <math.h>

#define DIM 256
#define HEADS 8
#define HD 32
#define T 1600
#define B 8
#define NBH (B * HEADS)
#define SCALE 0.17677669529663687f
#define EPS 1e-6f

// ---------------- Kernel 0: transpose first 512 rows of qkv_w ----------------
// W: (768, 256) row-major.  Wt: (256, 512), Wt[c*512 + r] = W[r*256 + c], r<512.
__global__ __launch_bounds__(256) void transpose_w(const float* __restrict__ W,
                                                   float* __restrict__ Wt) {
    int idx = blockIdx.x * 256 + threadIdx.x;  // 0 .. 512*256-1
    int r = idx & 511;                         // lane-consecutive -> coalesced store
    int c = idx >> 9;
    Wt[c * 512 + r] = W[r * 256 + c];
}

// ---------------- Kernel A: LayerNorm + QKV projection (q,k only) ----------------
// TOK=16 -> 800 blocks (3.1/CU) so Wt-load latency is hidden by TLP.
// Thread tid owns output channel tid (q) and tid+256 (k) for 16 tokens.
#define TOK 16
__global__ __launch_bounds__(256) void ln_qkv(const float* __restrict__ feat,
                                              const float* __restrict__ lnw,
                                              const float* __restrict__ lnb,
                                              const float* __restrict__ qkvb,
                                              const float* __restrict__ Wt,
                                              float* __restrict__ qws,
                                              float* __restrict__ ktws) {
    __shared__ float x[DIM * TOK];      // x[c][t], 16 KB
    __shared__ float red[2][16][TOK];
    __shared__ float mus[TOK], rstd[TOK];

    const int tid = threadIdx.x;
    const int blk = blockIdx.x;               // 0..799
    const int b = blk / (T / TOK);            // /100
    const int t0 = (blk % (T / TOK)) * TOK;

    const float* fb = feat + (size_t)b * DIM * T + t0;

    // load 256 channels x 16 tokens, float4 along t
    {
        const int c0 = tid >> 2;
        const int t4 = (tid & 3) * 4;
#pragma unroll
        for (int p = 0; p < 4; ++p) {
            int c = c0 + p * 64;
            float4 v = *(const float4*)(fb + (size_t)c * T + t4);
            *(float4*)&x[c * TOK + t4] = v;
        }
    }
    __syncthreads();

    const int g = tid >> 4;   // 0..15 channel group
    const int tp = tid & 15;  // token

    // LN stats: thread (g,tp) sums 16 channels of token tp
    float s = 0.f, sq = 0.f;
#pragma unroll
    for (int i = 0; i < 16; ++i) {
        float v = x[(g * 16 + i) * TOK + tp];
        s += v;
        sq += v * v;
    }
    red[0][g][tp] = s;
    red[1][g][tp] = sq;
    __syncthreads();
    if (tid < TOK) {
        float ts = 0.f, tq = 0.f;
#pragma unroll
        for (int i = 0; i < 16; ++i) { ts += red[0][i][tid]; tq += red[1][i][tid]; }
        float mu = ts * (1.f / DIM);
        float var = tq * (1.f / DIM) - mu * mu;
        mus[tid] = mu;
        rstd[tid] = rsqrtf(var + EPS);
    }
    __syncthreads();

    // normalize in LDS
#pragma unroll
    for (int i = 0; i < 16; ++i) {
        int c = g * 16 + i;
        float v = x[c * TOK + tp];
        x[c * TOK + tp] = (v - mus[tp]) * rstd[tp] * lnw[c] + lnb[c];
    }
    __syncthreads();

    // GEMM with 1-deep Wt prefetch; x reads are LDS broadcasts (b128-merged).
    float accq[TOK], acck[TOK];
#pragma unroll
    for (int t = 0; t < TOK; ++t) { accq[t] = 0.f; acck[t] = 0.f; }

    float wq = Wt[tid];
    float wk = Wt[256 + tid];
    for (int c = 0; c < DIM; ++c) {
        const int cn = (c + 1) & 255;         // dummy wrap on last iter (L1 hit)
        float wqn = Wt[cn * 512 + tid];
        float wkn = Wt[cn * 512 + 256 + tid];
        const float* xr = &x[c * TOK];
#pragma unroll
        for (int t = 0; t < TOK; ++t) {
            float xv = xr[t];
            accq[t] = fmaf(wq, xv, accq[t]);
            acck[t] = fmaf(wk, xv, acck[t]);
        }
        wq = wqn;
        wk = wkn;
    }

    const float bq = qkvb[tid];
    const float bk = qkvb[256 + tid];
    const int h = tid >> 5;
    const int d = tid & 31;

    float* qp = qws + ((size_t)(b * HEADS + h) * T + t0) * HD + d;
#pragma unroll
    for (int t = 0; t < TOK; ++t) qp[(size_t)t * HD] = (accq[t] + bq) * SCALE;

    float* kp = ktws + ((size_t)(b * HEADS + h) * HD + d) * T + t0;
#pragma unroll
    for (int tt = 0; tt < TOK / 4; ++tt) {
        float4 v;
        v.x = acck[4 * tt + 0] + bk;
        v.y = acck[4 * tt + 1] + bk;
        v.z = acck[4 * tt + 2] + bk;
        v.w = acck[4 * tt + 3] + bk;
        ((float4*)kp)[tt] = v;
    }
}

// ---------------- Kernel B: scores + softmax ----------------
// One block = 8 query rows of one (b,h); 1600 cols held in registers as float4:
// group0 = float4 idx tid (cols 4*tid..), group1 = float4 idx 256+tid (tid<144).
// K rows loaded as float4 with explicit 1-deep register double-buffer.
#define ROWS 8
#define NT4 (T / 4)  // 400 float4 per K row
__global__ __launch_bounds__(256, 4) void attn_softmax(const float* __restrict__ qws,
                                                       const float* __restrict__ ktws,
                                                       float* __restrict__ out) {
    __shared__ float qs[HD][ROWS];  // transposed q tile; rows 32B -> float4 broadcast
    __shared__ float redm[4][ROWS], redl[4][ROWS];

    const int tid = threadIdx.x;
    const int blk = blockIdx.x;               // 0..12799
    const int bh = blk / (T / ROWS);          // /200
    const int r0 = (blk % (T / ROWS)) * ROWS;

    {
        int i = tid >> 5, d = tid & 31;       // 256 threads = 8 rows x 32 d
        qs[d][i] = qws[((size_t)bh * T + r0 + i) * HD + d];
    }
    __syncthreads();

    float acc0[ROWS][4], acc1[ROWS][4];
#pragma unroll
    for (int i = 0; i < ROWS; ++i)
#pragma unroll
        for (int j = 0; j < 4; ++j) { acc0[i][j] = 0.f; acc1[i][j] = 0.f; }

    const bool g1 = tid < (NT4 - 256);        // tid < 144
    const int i1 = g1 ? 256 + tid : tid;      // clamped: always in-bounds
    const float4* kb4 = (const float4*)(ktws + (size_t)bh * HD * T);

    float4 kv0 = kb4[tid];
    float4 kv1 = kb4[i1];

    for (int d = 0; d < HD; ++d) {
        const float4* q4 = (const float4*)&qs[d][0];
        float4 qa = q4[0];
        float4 qb = q4[1];
        const int dn = (d + 1) & 31;          // dummy wrap prefetch on last iter
        float4 nk0 = kb4[dn * NT4 + tid];
        float4 nk1 = kb4[dn * NT4 + i1];

        float qv[8] = {qa.x, qa.y, qa.z, qa.w, qb.x, qb.y, qb.z, qb.w};
#pragma unroll
        for (int i = 0; i < ROWS; ++i) {
            acc0[i][0] = fmaf(qv[i], kv0.x, acc0[i][0]);
            acc0[i][1] = fmaf(qv[i], kv0.y, acc0[i][1]);
            acc0[i][2] = fmaf(qv[i], kv0.z, acc0[i][2]);
            acc0[i][3] = fmaf(qv[i], kv0.w, acc0[i][3]);
        }
        if (g1) {
#pragma unroll
            for (int i = 0; i < ROWS; ++i) {
                acc1[i][0] = fmaf(qv[i], kv1.x, acc1[i][0]);
                acc1[i][1] = fmaf(qv[i], kv1.y, acc1[i][1]);
                acc1[i][2] = fmaf(qv[i], kv1.z, acc1[i][2]);
                acc1[i][3] = fmaf(qv[i], kv1.w, acc1[i][3]);
            }
        }
        kv0 = nk0;
        kv1 = nk1;
    }

    const int w = tid >> 6;
    const int lane = tid & 63;

    // row max
    float m[ROWS];
#pragma unroll
    for (int i = 0; i < ROWS; ++i) {
        float v = fmaxf(fmaxf(acc0[i][0], acc0[i][1]), fmaxf(acc0[i][2], acc0[i][3]));
        if (g1) {
            float v1 = fmaxf(fmaxf(acc1[i][0], acc1[i][1]), fmaxf(acc1[i][2], acc1[i][3]));
            v = fmaxf(v, v1);
        }
#pragma unroll
        for (int off = 32; off; off >>= 1) v = fmaxf(v, __shfl_xor(v, off, 64));
        if (lane == 0) redm[w][i] = v;
    }
    __syncthreads();
#pragma unroll
    for (int i = 0; i < ROWS; ++i)
        m[i] = fmaxf(fmaxf(redm[0][i], redm[1][i]), fmaxf(redm[2][i], redm[3][i]));

    // exp + row sum
#pragma unroll
    for (int i = 0; i < ROWS; ++i) {
        float s = 0.f;
#pragma unroll
        for (int j = 0; j < 4; ++j) {
            float p = __expf(acc0[i][j] - m[i]);
            acc0[i][j] = p;
            s += p;
        }
        if (g1) {
#pragma unroll
            for (int j = 0; j < 4; ++j) {
                float p = __expf(acc1[i][j] - m[i]);
                acc1[i][j] = p;
                s += p;
            }
        }
#pragma unroll
        for (int off = 32; off; off >>= 1) s += __shfl_xor(s, off, 64);
        if (lane == 0) redl[w][i] = s;
    }
    __syncthreads();

    // store (float4, fully coalesced)
    float* ob = out + (size_t)bh * T * T + (size_t)r0 * T;
#pragma unroll
    for (int i = 0; i < ROWS; ++i) {
        float rinv = 1.0f / ((redl[0][i] + redl[1][i]) + (redl[2][i] + redl[3][i]));
        float4 o;
        o.x = acc0[i][0] * rinv;
        o.y = acc0[i][1] * rinv;
        o.z = acc0[i][2] * rinv;
        o.w = acc0[i][3] * rinv;
        ((float4*)(ob + (size_t)i * T))[tid] = o;
        if (g1) {
            float4 o1;
            o1.x = acc1[i][0] * rinv;
            o1.y = acc1[i][1] * rinv;
            o1.z = acc1[i][2] * rinv;
            o1.w = acc1[i][3] * rinv;
            ((float4*)(ob + (size_t)i * T))[256 + tid] = o1;
        }
    }
}

// ---------------- launch ----------------
extern "C" void kernel_launch(void* const* d_in, const int* in_sizes, int n_in,
                              void* d_out, int out_size, void* d_ws, size_t ws_size,
                              hipStream_t stream) {
    const float* feat = (const float*)d_in[0];
    const float* lnw = (const float*)d_in[1];
    const float* lnb = (const float*)d_in[2];
    const float* qkvw = (const float*)d_in[3];
    const float* qkvb = (const float*)d_in[4];
    float* out = (float*)d_out;

    float* Wt = (float*)d_ws;                        // 256*512 floats = 512 KB
    float* qws = Wt + 256 * 512;                     // NBH*T*HD = 3,276,800 floats
    float* ktws = qws + (size_t)NBH * T * HD;        // same size

    transpose_w<<<512, 256, 0, stream>>>(qkvw, Wt);
    ln_qkv<<<(B * T) / TOK, 256, 0, stream>>>(feat, lnw, lnb, qkvb, Wt, qws, ktws);
    attn_softmax<<<NBH * (T / ROWS), 256, 0, stream>>>(qws, ktws, out);
}

// Round 2
// 841.158 us; speedup vs baseline: 1.0330x; 1.0296x over previous
//
#include <hip/hip_runtime.h>
#include <math.h>

#define DIM 256
#define HEADS 8
#define HD 32
#define T 1600
#define B 8
#define NBH (B * HEADS)
#define SCALE 0.17677669529663687f
#define EPS 1e-6f

typedef float __attribute__((ext_vector_type(4))) f32x4;

// ---------------- Kernel 0: transpose first 512 rows of qkv_w ----------------
// W: (768, 256) row-major.  Wt: (256, 512), Wt[c*512 + r] = W[r*256 + c], r<512.
__global__ __launch_bounds__(256) void transpose_w(const float* __restrict__ W,
                                                   float* __restrict__ Wt) {
    int idx = blockIdx.x * 256 + threadIdx.x;  // 0 .. 512*256-1
    int r = idx & 511;                         // lane-consecutive -> coalesced store
    int c = idx >> 9;
    Wt[c * 512 + r] = W[r * 256 + c];
}

// ---------------- Kernel A: LayerNorm + QKV projection (q,k only) ----------------
// TOK=16 -> 800 blocks (3.1/CU) so Wt-load latency is hidden by TLP.
// Thread tid owns output channel tid (q) and tid+256 (k) for 16 tokens.
#define TOK 16
__global__ __launch_bounds__(256) void ln_qkv(const float* __restrict__ feat,
                                              const float* __restrict__ lnw,
                                              const float* __restrict__ lnb,
                                              const float* __restrict__ qkvb,
                                              const float* __restrict__ Wt,
                                              float* __restrict__ qws,
                                              float* __restrict__ ktws) {
    __shared__ float x[DIM * TOK];      // x[c][t], 16 KB
    __shared__ float red[2][16][TOK];
    __shared__ float mus[TOK], rstd[TOK];

    const int tid = threadIdx.x;
    const int blk = blockIdx.x;               // 0..799
    const int b = blk / (T / TOK);            // /100
    const int t0 = (blk % (T / TOK)) * TOK;

    const float* fb = feat + (size_t)b * DIM * T + t0;

    // load 256 channels x 16 tokens, float4 along t
    {
        const int c0 = tid >> 2;
        const int t4 = (tid & 3) * 4;
#pragma unroll
        for (int p = 0; p < 4; ++p) {
            int c = c0 + p * 64;
            float4 v = *(const float4*)(fb + (size_t)c * T + t4);
            *(float4*)&x[c * TOK + t4] = v;
        }
    }
    __syncthreads();

    const int g = tid >> 4;   // 0..15 channel group
    const int tp = tid & 15;  // token

    // LN stats: thread (g,tp) sums 16 channels of token tp
    float s = 0.f, sq = 0.f;
#pragma unroll
    for (int i = 0; i < 16; ++i) {
        float v = x[(g * 16 + i) * TOK + tp];
        s += v;
        sq += v * v;
    }
    red[0][g][tp] = s;
    red[1][g][tp] = sq;
    __syncthreads();
    if (tid < TOK) {
        float ts = 0.f, tq = 0.f;
#pragma unroll
        for (int i = 0; i < 16; ++i) { ts += red[0][i][tid]; tq += red[1][i][tid]; }
        float mu = ts * (1.f / DIM);
        float var = tq * (1.f / DIM) - mu * mu;
        mus[tid] = mu;
        rstd[tid] = rsqrtf(var + EPS);
    }
    __syncthreads();

    // normalize in LDS
#pragma unroll
    for (int i = 0; i < 16; ++i) {
        int c = g * 16 + i;
        float v = x[c * TOK + tp];
        x[c * TOK + tp] = (v - mus[tp]) * rstd[tp] * lnw[c] + lnb[c];
    }
    __syncthreads();

    // GEMM with 1-deep Wt prefetch; x reads are LDS broadcasts (b128-merged).
    float accq[TOK], acck[TOK];
#pragma unroll
    for (int t = 0; t < TOK; ++t) { accq[t] = 0.f; acck[t] = 0.f; }

    float wq = Wt[tid];
    float wk = Wt[256 + tid];
    for (int c = 0; c < DIM; ++c) {
        const int cn = (c + 1) & 255;         // dummy wrap on last iter (L1 hit)
        float wqn = Wt[cn * 512 + tid];
        float wkn = Wt[cn * 512 + 256 + tid];
        const float* xr = &x[c * TOK];
#pragma unroll
        for (int t = 0; t < TOK; ++t) {
            float xv = xr[t];
            accq[t] = fmaf(wq, xv, accq[t]);
            acck[t] = fmaf(wk, xv, acck[t]);
        }
        wq = wqn;
        wk = wkn;
    }

    const float bq = qkvb[tid];
    const float bk = qkvb[256 + tid];
    const int h = tid >> 5;
    const int d = tid & 31;

    float* qp = qws + ((size_t)(b * HEADS + h) * T + t0) * HD + d;
#pragma unroll
    for (int t = 0; t < TOK; ++t) qp[(size_t)t * HD] = (accq[t] + bq) * SCALE;

    float* kp = ktws + ((size_t)(b * HEADS + h) * HD + d) * T + t0;
#pragma unroll
    for (int tt = 0; tt < TOK / 4; ++tt) {
        float4 v;
        v.x = acck[4 * tt + 0] + bk;
        v.y = acck[4 * tt + 1] + bk;
        v.z = acck[4 * tt + 2] + bk;
        v.w = acck[4 * tt + 3] + bk;
        ((float4*)kp)[tt] = v;
    }
}

// ---------------- Kernel B: scores + softmax ----------------
// One block = 8 query rows of one (b,h); 1600 cols in registers as float4:
// group0 = float4 idx tid, group1 = float4 idx 256+tid (tid<144 only).
// XCD-aware swizzle keeps each bh's K-panel resident in ONE XCD's L2;
// nontemporal output stores keep the 655 MB write stream from evicting it.
#define ROWS 8
#define NT4 (T / 4)  // 400 float4 per K row
__global__ __launch_bounds__(256) void attn_softmax(const float* __restrict__ qws,
                                                    const float* __restrict__ ktws,
                                                    float* __restrict__ out) {
    __shared__ float qs[HD][ROWS];  // transposed q tile; rows 32B -> float4 broadcast
    __shared__ float redm[4][ROWS], redl[4][ROWS];

    const int tid = threadIdx.x;
    // XCD swizzle: 12800 blocks, 8 XCDs, round-robin dispatch ->
    // give each XCD a contiguous 1600-block chunk (= 8 whole bh panels).
    const int blk = (blockIdx.x & 7) * (NBH * (T / ROWS) / 8) + (blockIdx.x >> 3);
    const int bh = blk / (T / ROWS);          // /200
    const int r0 = (blk % (T / ROWS)) * ROWS;

    {
        int i = tid >> 5, d = tid & 31;       // 256 threads = 8 rows x 32 d
        qs[d][i] = qws[((size_t)bh * T + r0 + i) * HD + d];
    }
    __syncthreads();

    float acc0[ROWS][4], acc1[ROWS][4];
#pragma unroll
    for (int i = 0; i < ROWS; ++i)
#pragma unroll
        for (int j = 0; j < 4; ++j) { acc0[i][j] = 0.f; acc1[i][j] = 0.f; }

    const bool g1 = tid < (NT4 - 256);        // tid < 144
    const float4* kb4 = (const float4*)(ktws + (size_t)bh * HD * T);

    float4 kv0 = kb4[tid];
    float4 kv1;
    if (g1) kv1 = kb4[256 + tid];

    for (int d = 0; d < HD; ++d) {
        const float4* q4 = (const float4*)&qs[d][0];
        float4 qa = q4[0];
        float4 qb = q4[1];
        const int dn = (d + 1) & 31;          // dummy wrap prefetch on last iter
        float4 nk0 = kb4[dn * NT4 + tid];

        float qv[8] = {qa.x, qa.y, qa.z, qa.w, qb.x, qb.y, qb.z, qb.w};
#pragma unroll
        for (int i = 0; i < ROWS; ++i) {
            acc0[i][0] = fmaf(qv[i], kv0.x, acc0[i][0]);
            acc0[i][1] = fmaf(qv[i], kv0.y, acc0[i][1]);
            acc0[i][2] = fmaf(qv[i], kv0.z, acc0[i][2]);
            acc0[i][3] = fmaf(qv[i], kv0.w, acc0[i][3]);
        }
        if (g1) {
            float4 nk1 = kb4[dn * NT4 + 256 + tid];
#pragma unroll
            for (int i = 0; i < ROWS; ++i) {
                acc1[i][0] = fmaf(qv[i], kv1.x, acc1[i][0]);
                acc1[i][1] = fmaf(qv[i], kv1.y, acc1[i][1]);
                acc1[i][2] = fmaf(qv[i], kv1.z, acc1[i][2]);
                acc1[i][3] = fmaf(qv[i], kv1.w, acc1[i][3]);
            }
            kv1 = nk1;
        }
        kv0 = nk0;
    }

    const int w = tid >> 6;
    const int lane = tid & 63;

    // row max
    float m[ROWS];
#pragma unroll
    for (int i = 0; i < ROWS; ++i) {
        float v = fmaxf(fmaxf(acc0[i][0], acc0[i][1]), fmaxf(acc0[i][2], acc0[i][3]));
        if (g1) {
            float v1 = fmaxf(fmaxf(acc1[i][0], acc1[i][1]), fmaxf(acc1[i][2], acc1[i][3]));
            v = fmaxf(v, v1);
        }
#pragma unroll
        for (int off = 32; off; off >>= 1) v = fmaxf(v, __shfl_xor(v, off, 64));
        if (lane == 0) redm[w][i] = v;
    }
    __syncthreads();
#pragma unroll
    for (int i = 0; i < ROWS; ++i)
        m[i] = fmaxf(fmaxf(redm[0][i], redm[1][i]), fmaxf(redm[2][i], redm[3][i]));

    // exp + row sum
#pragma unroll
    for (int i = 0; i < ROWS; ++i) {
        float s = 0.f;
#pragma unroll
        for (int j = 0; j < 4; ++j) {
            float p = __expf(acc0[i][j] - m[i]);
            acc0[i][j] = p;
            s += p;
        }
        if (g1) {
#pragma unroll
            for (int j = 0; j < 4; ++j) {
                float p = __expf(acc1[i][j] - m[i]);
                acc1[i][j] = p;
                s += p;
            }
        }
#pragma unroll
        for (int off = 32; off; off >>= 1) s += __shfl_xor(s, off, 64);
        if (lane == 0) redl[w][i] = s;
    }
    __syncthreads();

    // store: nontemporal float4 -> don't let the 655 MB stream evict K from L2
    float* ob = out + (size_t)bh * T * T + (size_t)r0 * T;
#pragma unroll
    for (int i = 0; i < ROWS; ++i) {
        float rinv = 1.0f / ((redl[0][i] + redl[1][i]) + (redl[2][i] + redl[3][i]));
        f32x4 o;
        o.x = acc0[i][0] * rinv;
        o.y = acc0[i][1] * rinv;
        o.z = acc0[i][2] * rinv;
        o.w = acc0[i][3] * rinv;
        __builtin_nontemporal_store(o, (f32x4*)(ob + (size_t)i * T) + tid);
        if (g1) {
            f32x4 o1;
            o1.x = acc1[i][0] * rinv;
            o1.y = acc1[i][1] * rinv;
            o1.z = acc1[i][2] * rinv;
            o1.w = acc1[i][3] * rinv;
            __builtin_nontemporal_store(o1, (f32x4*)(ob + (size_t)i * T) + 256 + tid);
        }
    }
}

// ---------------- launch ----------------
extern "C" void kernel_launch(void* const* d_in, const int* in_sizes, int n_in,
                              void* d_out, int out_size, void* d_ws, size_t ws_size,
                              hipStream_t stream) {
    const float* feat = (const float*)d_in[0];
    const float* lnw = (const float*)d_in[1];
    const float* lnb = (const float*)d_in[2];
    const float* qkvw = (const float*)d_in[3];
    const float* qkvb = (const float*)d_in[4];
    float* out = (float*)d_out;

    float* Wt = (float*)d_ws;                        // 256*512 floats = 512 KB
    float* qws = Wt + 256 * 512;                     // NBH*T*HD = 3,276,800 floats
    float* ktws = qws + (size_t)NBH * T * HD;        // same size

    transpose_w<<<512, 256, 0, stream>>>(qkvw, Wt);
    ln_qkv<<<(B * T) / TOK, 256, 0, stream>>>(feat, lnw, lnb, qkvb, Wt, qws, ktws);
    attn_softmax<<<NBH * (T / ROWS), 256, 0, stream>>>(qws, ktws, out);
}